// Round 9
// baseline (121.553 us; speedup 1.0000x reference)
//
#include <hip/hip_runtime.h>
#include <math.h>

typedef _Float16 v8h __attribute__((ext_vector_type(8)));
typedef float v4f __attribute__((ext_vector_type(4)));

#define MFMA16(a, b, c) __builtin_amdgcn_mfma_f32_16x16x32_f16((a), (b), (c), 0, 0, 0)

// swizzled tile addressing (byte offsets)
#define TA64(row, colb)  ((((row) * 128) + (colb)) ^ (((row) & 7) << 4))
#define TA128(row, colb) ((((row) * 256) + (colb)) ^ (((row) & 15) << 4))

__device__ __forceinline__ unsigned int pk_f16(float a, float b) {
    return __builtin_bit_cast(unsigned int, __builtin_amdgcn_cvt_pkrtz(a, b));
}

// ---------------------------------------------------------------- k_prep ----
// Wt[c][d] = fp16(W_w[d][c]); wallT[p][o][k] = fp16(w_p[k][o]); sc/bi fold BN.
__global__ __launch_bounds__(256) void k_prep(
    const float* __restrict__ tw, const float* __restrict__ pw,
    const float* __restrict__ gw,
    const float* __restrict__ Ww, const float* __restrict__ Wb,
    const float* __restrict__ gamma, const float* __restrict__ beta,
    const float* __restrict__ mean, const float* __restrict__ var,
    _Float16* __restrict__ Wt, _Float16* __restrict__ wallT,
    float* __restrict__ sc, float* __restrict__ bi)
{
    int t = threadIdx.x;
    #pragma unroll
    for (int rep = 0; rep < 32; ++rep) {
        int idx = rep * 256 + t;          // 64*128
        int d = idx >> 7, c = idx & 127;
        Wt[c * 64 + d] = (_Float16)Ww[idx];
    }
    for (int rep = 0; rep < 96; ++rep) {  // 3*64*128 transposed fp16 weights
        int idx = rep * 256 + t;
        int p = idx >> 13, rem = idx & 8191;
        int o = rem >> 7, k = rem & 127;
        const float* wm = (p == 0) ? tw : (p == 1) ? pw : gw;
        wallT[idx] = (_Float16)wm[k * 64 + o];
    }
    if (t < 128) {
        float inv = gamma[t] * rsqrtf(var[t] + 1e-4f);
        sc[t] = inv;
        bi[t] = (Wb[t] - mean[t]) * inv + beta[t];
    }
}

// ---------------------------------------------------------------- k_proj ----
// fp16 MFMA projections, ZERO LDS / ZERO barriers. Grid 256 x 512 threads.
// Wave w: 16 tokens. A = x (direct global fp32 -> fp16 frags), B = wallT
// (direct global, L2-hot). D: col=lane&15 = out-dim, row = 4hi+rr = token.
__global__ __launch_bounds__(512, 4) void k_proj(
    const float* __restrict__ x, const _Float16* __restrict__ wallT,
    const float* __restrict__ tb, const float* __restrict__ pb,
    const float* __restrict__ gb,
    _Float16* __restrict__ theta, _Float16* __restrict__ phi,
    _Float16* __restrict__ gT)
{
    const int t = threadIdx.x;
    const int w = t >> 6, l = t & 63, hi = l >> 4, lo = l & 15;
    const int tok0 = blockIdx.x * 128 + w * 16;

    // A-frags: x[tok0+lo][kc*32 + hi*8 .. +7] -> fp16
    v8h xA[4];
    #pragma unroll
    for (int kc = 0; kc < 4; ++kc) {
        const float* px = x + (size_t)(tok0 + lo) * 128 + kc * 32 + hi * 8;
        float4 f0 = *(const float4*)(px);
        float4 f1 = *(const float4*)(px + 4);
        uint4 u;
        u.x = pk_f16(f0.x, f0.y); u.y = pk_f16(f0.z, f0.w);
        u.z = pk_f16(f1.x, f1.y); u.w = pk_f16(f1.z, f1.w);
        xA[kc] = __builtin_bit_cast(v8h, u);
    }

    #pragma unroll
    for (int p = 0; p < 3; ++p) {
        const _Float16* wp = wallT + p * 8192;
        const float* bias = (p == 0) ? tb : (p == 1) ? pb : gb;
        #pragma unroll
        for (int oc = 0; oc < 4; ++oc) {
            int o = oc * 16 + lo;
            v4f acc = (v4f){0.f, 0.f, 0.f, 0.f};
            #pragma unroll
            for (int kc = 0; kc < 4; ++kc) {
                v8h B = *(const v8h*)(wp + o * 128 + kc * 32 + hi * 8);
                acc = MFMA16(xA[kc], B, acc);
            }
            float bv = bias[o];
            if (p < 2) {
                _Float16* dst = (p == 0) ? theta : phi;
                #pragma unroll
                for (int rr = 0; rr < 4; ++rr)
                    dst[(size_t)(tok0 + 4 * hi + rr) * 64 + o] =
                        (_Float16)(acc[rr] + bv);
            } else {
                int tokg = tok0 + 4 * hi;
                int bb = tokg >> 12, n0 = tokg & 4095;
                uint2 pk;
                pk.x = pk_f16(acc[0] + bv, acc[1] + bv);
                pk.y = pk_f16(acc[2] + bv, acc[3] + bv);
                *(uint2*)(gT + ((size_t)bb * 64 + o) * 4096 + n0) = pk;
            }
        }
    }
}

// ---------------------------------------------------------------- k_attn ----
// Flash attention + fused epilogue. Grid (64,8) = 512 blocks, 512 thr = 8 waves
// = 2 qt (32 queries) x 4 kh (32-key quarter of each 128-key tile).
// phi: DIRECT global->reg A-frags (no LDS). gv (=g^T): LDS-staged TA128.
// P: per-wave LDS scr (TA64, 32 rows). 4-way kh flash-combine at end via
// normalized fp16 partials u=y/l + z=m+ln(l). Epilogue on kh=0 waves.
__global__ __launch_bounds__(512, 4) void k_attn(
    const _Float16* __restrict__ theta,
    const _Float16* __restrict__ phi,
    const _Float16* __restrict__ gT,
    const _Float16* __restrict__ Wt,
    const float* __restrict__ sc, const float* __restrict__ bi,
    const float* __restrict__ x, float* __restrict__ out)
{
    __shared__ __align__(16) _Float16 gv_l[64 * 128];   // 16KB (+z scratch)
    __shared__ __align__(16) _Float16 scr[8][32 * 64];  // 32KB P / u / y

    const int t = threadIdx.x;
    const int w = t >> 6, l = t & 63, hi = l >> 4, lo = l & 15;
    const int qt = w & 1, kh = w >> 1;
    const int b = blockIdx.y, qb = blockIdx.x;
    const int q0 = qb * 64 + qt * 32;
    const size_t tok0 = (size_t)b * 4096 + q0;

    char* gvL = (char*)gv_l;
    char* scrc = (char*)&scr[w][0];
    char* scr0 = (char*)&scr[0][0];

    v8h thA[2][2];                       // [qfrag][kc]
    #pragma unroll
    for (int f = 0; f < 2; ++f)
        #pragma unroll
        for (int kc = 0; kc < 2; ++kc)
            thA[f][kc] = *(const v8h*)(theta +
                (tok0 + f * 16 + lo) * 64 + kc * 32 + hi * 8);

    const _Float16* phb = phi + (size_t)b * 4096 * 64;
    const _Float16* gvb = gT + (size_t)b * 64 * 4096;

    v4f yacc[2][4];                      // y[q=f*16+4hi+rr][d=16dt+lo]
    #pragma unroll
    for (int f = 0; f < 2; ++f)
        #pragma unroll
        for (int dt = 0; dt < 4; ++dt) yacc[f][dt] = (v4f){0.f, 0.f, 0.f, 0.f};
    float mrow[2] = {-INFINITY, -INFINITY}, lrow[2] = {0.f, 0.f};

    // gv staging: 64x128 tile, 2 chunks/thread
    const int gvr = t >> 4, gvcB = (t & 15) * 16;
    const int gvA0 = TA128(gvr, gvcB), gvA1 = TA128(gvr + 32, gvcB);
    const _Float16* pGv = gvb + (size_t)gvr * 4096 + (gvcB >> 1);
    // phi direct-load base: rows kh*32 + {s*16} + lo, k = {half*32} + hi*8
    const _Float16* pPhi = phb + (size_t)(kh * 32 + lo) * 64 + hi * 8;

    v8h pf2 = *(const v8h*)(pGv);
    v8h pf3 = *(const v8h*)(pGv + (size_t)32 * 4096);
    pGv += 128;

    for (int kt = 0; kt < 32; ++kt) {
        __syncthreads();                 // prev tile consumed
        *(v8h*)(gvL + gvA0) = pf2;
        *(v8h*)(gvL + gvA1) = pf3;
        __syncthreads();
        if (kt < 31) {
            pf2 = *(const v8h*)(pGv);
            pf3 = *(const v8h*)(pGv + (size_t)32 * 4096);
            pGv += 128;
        }
        // ---- phi A-frags direct from global (L1/L2-hot)
        v8h a00 = *(const v8h*)(pPhi);          // s=0, k 0..31
        v8h a01 = *(const v8h*)(pPhi + 32);     // s=0, k 32..63
        v8h a10 = *(const v8h*)(pPhi + 1024);   // s=1 (16 rows * 64)
        v8h a11 = *(const v8h*)(pPhi + 1056);
        pPhi += 8192;                            // 128 rows * 64
        // ---- QK^T: S[f][s] -> P[key=kh*32+s*16+4hi+rr][q=tok0+f*16+lo]
        v4f S[2][2];
        __builtin_amdgcn_s_setprio(1);
        #pragma unroll
        for (int f = 0; f < 2; ++f) {
            v4f c0 = MFMA16(a00, thA[f][0], ((v4f){0.f, 0.f, 0.f, 0.f}));
            S[f][0] = MFMA16(a01, thA[f][1], c0);
            v4f c1 = MFMA16(a10, thA[f][0], ((v4f){0.f, 0.f, 0.f, 0.f}));
            S[f][1] = MFMA16(a11, thA[f][1], c1);
        }
        __builtin_amdgcn_s_setprio(0);
        // ---- online softmax, two streams (q = tok0+f*16+lo)
        float vmax[2], aa[2];
        #pragma unroll
        for (int f = 0; f < 2; ++f) {
            float v = fmaxf(fmaxf(fmaxf(S[f][0][0], S[f][0][1]),
                                  fmaxf(S[f][0][2], S[f][0][3])),
                            fmaxf(fmaxf(S[f][1][0], S[f][1][1]),
                                  fmaxf(S[f][1][2], S[f][1][3])));
            v = fmaxf(v, __shfl_xor(v, 16));
            v = fmaxf(v, __shfl_xor(v, 32));
            vmax[f] = v;
            aa[f] = 1.0f;
        }
        bool ok = (vmax[0] <= mrow[0] + 8.0f) && (vmax[1] <= mrow[1] + 8.0f);
        if (!__all(ok)) {                // defer-max (THR=8)
            #pragma unroll
            for (int f = 0; f < 2; ++f) {
                float mn = fmaxf(mrow[f], vmax[f]);
                aa[f] = __expf(mrow[f] - mn);
                mrow[f] = mn;
            }
            float aq[2][4];
            #pragma unroll
            for (int f = 0; f < 2; ++f)
                #pragma unroll
                for (int rr = 0; rr < 4; ++rr)
                    aq[f][rr] = __shfl(aa[f], 20 * hi + rr);
            #pragma unroll
            for (int f = 0; f < 2; ++f)
                #pragma unroll
                for (int dt = 0; dt < 4; ++dt)
                    #pragma unroll
                    for (int rr = 0; rr < 4; ++rr)
                        yacc[f][dt][rr] *= aq[f][rr];
        }
        #pragma unroll
        for (int f = 0; f < 2; ++f) {
            float psum = 0.f;
            #pragma unroll
            for (int s = 0; s < 2; ++s) {
                #pragma unroll
                for (int rr = 0; rr < 4; ++rr)
                    S[f][s][rr] = __expf(S[f][s][rr] - mrow[f]);
                psum += (S[f][s][0] + S[f][s][1]) + (S[f][s][2] + S[f][s][3]);
            }
            psum += __shfl_xor(psum, 16);
            psum += __shfl_xor(psum, 32);
            lrow[f] = lrow[f] * aa[f] + psum;
        }
        // ---- P -> scr (row = f*16+lo, key byte = s*32 + hi*8)
        #pragma unroll
        for (int f = 0; f < 2; ++f)
            #pragma unroll
            for (int s = 0; s < 2; ++s) {
                uint2 pk;
                pk.x = pk_f16(S[f][s][0], S[f][s][1]);
                pk.y = pk_f16(S[f][s][2], S[f][s][3]);
                *(uint2*)(scrc + TA64(f * 16 + lo, s * 32 + hi * 8)) = pk;
            }
        // ---- PV: each gB feeds both q-frags
        v8h pA[2];
        #pragma unroll
        for (int f = 0; f < 2; ++f)
            pA[f] = *(const v8h*)(scrc + TA64(f * 16 + lo, hi * 16));
        __builtin_amdgcn_s_setprio(1);
        #pragma unroll
        for (int dt = 0; dt < 4; ++dt) {
            v8h gB = *(const v8h*)(gvL + TA128(dt * 16 + lo, kh * 64 + hi * 16));
            yacc[0][dt] = MFMA16(pA[0], gB, yacc[0][dt]);
            yacc[1][dt] = MFMA16(pA[1], gB, yacc[1][dt]);
        }
        __builtin_amdgcn_s_setprio(0);
    }

    // ---- write normalized partial u = y/l (fp16) to own scr slot
    float invl[2][4];
    #pragma unroll
    for (int f = 0; f < 2; ++f)
        #pragma unroll
        for (int rr = 0; rr < 4; ++rr)
            invl[f][rr] = 1.0f / __shfl(lrow[f], 20 * hi + rr);
    #pragma unroll
    for (int j = 0; j < 4; ++j) {        // chunk j covers e = 8j..8j+7
        uint4 u;
        unsigned int wds[4];
        #pragma unroll
        for (int k = 0; k < 4; ++k) {
            int e0 = 8 * j + 2 * k;
            int f0 = e0 >> 4, d0 = (e0 >> 2) & 3, r0 = e0 & 3;
            int e1 = e0 + 1;
            int f1 = e1 >> 4, d1 = (e1 >> 2) & 3, r1 = e1 & 3;
            wds[k] = pk_f16(yacc[f0][d0][r0] * invl[f0][r0],
                            yacc[f1][d1][r1] * invl[f1][r1]);
        }
        u.x = wds[0]; u.y = wds[1]; u.z = wds[2]; u.w = wds[3];
        *(uint4*)(scrc + l * 64 + j * 16) = u;
    }
    __syncthreads();                     // all PV/gv reads done
    float* zf = (float*)gv_l;            // z scratch [8 slots][2 f][16 lo]
    zf[w * 32 + 0 * 16 + lo] = mrow[0] + __logf(lrow[0]);
    zf[w * 32 + 1 * 16 + lo] = mrow[1] + __logf(lrow[1]);
    __syncthreads();
    if (w >= 2) return;

    // ---- combine 4 kh partials (slots w, w+2, w+4, w+6); qt = w
    float zq[4][2][4];                   // [kp][f][rr]
    #pragma unroll
    for (int kp = 0; kp < 4; ++kp) {
        int ws = kp * 2 + qt;
        #pragma unroll
        for (int f = 0; f < 2; ++f)
            #pragma unroll
            for (int rr = 0; rr < 4; ++rr)
                zq[kp][f][rr] = zf[ws * 32 + f * 16 + 4 * hi + rr];
    }
    float wsum[2][4], zmx[2][4];
    #pragma unroll
    for (int f = 0; f < 2; ++f)
        #pragma unroll
        for (int rr = 0; rr < 4; ++rr) {
            float m01 = fmaxf(zq[0][f][rr], zq[1][f][rr]);
            float m23 = fmaxf(zq[2][f][rr], zq[3][f][rr]);
            zmx[f][rr] = fmaxf(m01, m23);
            wsum[f][rr] = 0.f;
        }
    float yfin[2][4][4];
    #pragma unroll
    for (int f = 0; f < 2; ++f)
        #pragma unroll
        for (int dt = 0; dt < 4; ++dt)
            #pragma unroll
            for (int rr = 0; rr < 4; ++rr) yfin[f][dt][rr] = 0.f;
    #pragma unroll
    for (int kp = 0; kp < 4; ++kp) {
        int ws = kp * 2 + qt;
        v8h c[4];
        #pragma unroll
        for (int j = 0; j < 4; ++j)
            c[j] = *(const v8h*)(scr0 + ws * 4096 + l * 64 + j * 16);
        float wk[2][4];
        #pragma unroll
        for (int f = 0; f < 2; ++f)
            #pragma unroll
            for (int rr = 0; rr < 4; ++rr) {
                wk[f][rr] = __expf(zq[kp][f][rr] - zmx[f][rr]);
                wsum[f][rr] += wk[f][rr];
            }
        #pragma unroll
        for (int f = 0; f < 2; ++f)
            #pragma unroll
            for (int dt = 0; dt < 4; ++dt)
                #pragma unroll
                for (int rr = 0; rr < 4; ++rr) {
                    int e = f * 16 + dt * 4 + rr;
                    yfin[f][dt][rr] += wk[f][rr] * (float)c[e >> 3][e & 7];
                }
    }
    // ---- y (normalized) -> scr fp16 for epilogue A-frags
    #pragma unroll
    for (int f = 0; f < 2; ++f)
        #pragma unroll
        for (int rr = 0; rr < 4; ++rr) {
            float inv = 1.0f / wsum[f][rr];
            #pragma unroll
            for (int dt = 0; dt < 4; ++dt)
                *(_Float16*)(scrc + TA64(f * 16 + 4 * hi + rr,
                                         (dt * 16 + lo) * 2)) =
                    (_Float16)(yfin[f][dt][rr] * inv);
        }
    v8h yA[2][2];
    #pragma unroll
    for (int f = 0; f < 2; ++f)
        #pragma unroll
        for (int kc = 0; kc < 2; ++kc)
            yA[f][kc] = *(const v8h*)(scrc + TA64(f * 16 + lo,
                                                  kc * 64 + hi * 16));
    // ---- epilogue: wy = y @ W^T -> BN + residual
    const float* xb = x + tok0 * 128;
    float* ob = out + tok0 * 128;
    #pragma unroll
    for (int ct = 0; ct < 8; ++ct) {
        int c = ct * 16 + lo;
        v8h wB0 = *(const v8h*)(Wt + c * 64 + hi * 8);
        v8h wB1 = *(const v8h*)(Wt + c * 64 + 32 + hi * 8);
        float scc = sc[c], bic = bi[c];
        #pragma unroll
        for (int f = 0; f < 2; ++f) {
            v4f wy = MFMA16(yA[f][0], wB0, ((v4f){0.f, 0.f, 0.f, 0.f}));
            wy = MFMA16(yA[f][1], wB1, wy);
            #pragma unroll
            for (int rr = 0; rr < 4; ++rr) {
                int m = f * 16 + 4 * hi + rr;
                ob[(size_t)m * 128 + c] =
                    wy[rr] * scc + bic + xb[(size_t)m * 128 + c];
            }
        }
    }
}

// ------------------------------------------------------------------ launch --
extern "C" void kernel_launch(void* const* d_in, const int* in_sizes, int n_in,
                              void* d_out, int out_size, void* d_ws, size_t ws_size,
                              hipStream_t stream) {
    const float* x     = (const float*)d_in[0];
    const float* tw    = (const float*)d_in[1];
    const float* tb    = (const float*)d_in[2];
    const float* pw    = (const float*)d_in[3];
    const float* pb    = (const float*)d_in[4];
    const float* gw    = (const float*)d_in[5];
    const float* gb    = (const float*)d_in[6];
    const float* Ww    = (const float*)d_in[7];
    const float* Wb    = (const float*)d_in[8];
    const float* gamma = (const float*)d_in[9];
    const float* beta  = (const float*)d_in[10];
    const float* mean  = (const float*)d_in[11];
    const float* var   = (const float*)d_in[12];

    char* ws = (char*)d_ws;
    _Float16* theta = (_Float16*)ws;                       // 4 MB
    _Float16* phi   = (_Float16*)(ws + (4u << 20));        // 4 MB
    _Float16* gT    = (_Float16*)(ws + (8u << 20));        // 4 MB
    _Float16* Wt    = (_Float16*)(ws + (12u << 20));       // 16 KB
    _Float16* wallT = (_Float16*)(ws + (12u << 20) + (1u << 16));  // 48 KB
    float* sc       = (float*)(ws + (12u << 20) + (2u << 16));
    float* bi       = sc + 128;

    k_prep<<<1, 256, 0, stream>>>(tw, pw, gw, Ww, Wb, gamma, beta, mean, var,
                                  Wt, wallT, sc, bi);
    k_proj<<<256, 512, 0, stream>>>(x, wallT, tb, pb, gb, theta, phi, gT);
    k_attn<<<dim3(64, 8), 512, 0, stream>>>(theta, phi, gT, Wt, sc, bi,
                                            x, (float*)d_out);
}